// Round 1
// baseline (562.778 us; speedup 1.0000x reference)
//
#include <hip/hip_runtime.h>

// RGCN 2-layer: N=100000 nodes, E=3200000 edges, R=8 relations, H=C=16.
// Strategy: per-wave 16-edge tiles; block-sparse A[16x128] @ concat(W_r)[128x16]
// via 4x mfma_f32_16x16x32_bf16; coalesced f32 atomic scatter into agg[dst].
// Node epilogues (root-matmul + bias + relu / log_softmax) as 1-MFMA tiles.

constexpr int N_NODES = 100000;
constexpr int N_EDGES = 3200000;
constexpr int NREL = 8;

typedef short bf16x8 __attribute__((ext_vector_type(8)));
typedef float f32x4 __attribute__((ext_vector_type(4)));

__device__ __forceinline__ short f2bf(float f) {
  union { float f; unsigned u; } v; v.f = f;
  unsigned r = v.u + 0x7FFFu + ((v.u >> 16) & 1u);  // RNE
  return (short)(r >> 16);
}

// K1: per-(dst, relation) edge counts. E divisible by 256 -> no guard.
__global__ void __launch_bounds__(256) count_kernel(
    const int* __restrict__ dst, const int* __restrict__ typ,
    unsigned* __restrict__ cnt) {
  int e = blockIdx.x * 256 + threadIdx.x;
  atomicAdd(&cnt[(unsigned)dst[e] * NREL + (unsigned)typ[e]], 1u);
}

// K2: invc = 1 / max(cnt, 1)
__global__ void __launch_bounds__(256) inv_kernel(
    const unsigned* __restrict__ cnt, float* __restrict__ invc) {
  int i = blockIdx.x * 256 + threadIdx.x;
  if (i < N_NODES * NREL) {
    unsigned c = cnt[i];
    invc[i] = 1.0f / (float)(c ? c : 1u);
  }
}

// K3/K5: edge message + scatter.
// Wave tile = 16 edges. A[16x128]: row e = x[src_e]*norm_e placed in column
// block 16*t_e. B[128x16] = vertical concat of W_r. D = A.B -> msg tile.
// Fragment layout (canonical CDNA, C/D verified m89):
//   A: lane l holds row (l&15), k = m*32 + (l>>4)*8 + j
//   B: lane l holds col (l&15), same k
//   D: lane l holds col (l&15), row = (l>>4)*4 + reg
__global__ void __launch_bounds__(256) edge_kernel(
    const float* __restrict__ X, const float* __restrict__ W,
    const float* __restrict__ invc, const int* __restrict__ src,
    const int* __restrict__ dst, const int* __restrict__ typ,
    float* __restrict__ agg) {
  const int lid  = threadIdx.x & 63;
  const int col  = lid & 15;
  const int quad = lid >> 4;
  const int wid  = (int)((blockIdx.x * 256u + threadIdx.x) >> 6);
  const int nw   = (int)((gridDim.x * 256u) >> 6);

  // B fragments (registers, loaded once per wave): for MFMA m,
  // k = m*32 + quad*8 + j -> relation r = 2m + (kq>>4), kk = kq&15.
  bf16x8 b0, b1, b2, b3;
#pragma unroll
  for (int j = 0; j < 8; ++j) {
    int kq = quad * 8 + j;
    int rb = kq >> 4;       // 0 or 1
    int kk = kq & 15;
    b0[j] = f2bf(W[(rb + 0) * 256 + kk * 16 + col]);
    b1[j] = f2bf(W[(rb + 2) * 256 + kk * 16 + col]);
    b2[j] = f2bf(W[(rb + 4) * 256 + kk * 16 + col]);
    b3[j] = f2bf(W[(rb + 6) * 256 + kk * 16 + col]);
  }

  const int NT = N_EDGES / 16;
  for (int tile = wid; tile < NT; tile += nw) {
    const int e0 = tile * 16;
    // This lane builds A-row (lid&15) == col.
    const int sr = src[e0 + col];
    const int dt = dst[e0 + col];
    const int tp = typ[e0 + col];
    const float nrm = invc[dt * NREL + tp];

    // Lane's k-chunks hit relation r = 2m + (quad>>1); active iff r == tp
    // for m = tp>>1, i.e. (quad>>1) == (tp&1). kk offset = (quad&1)*8.
    bf16x8 av = {0, 0, 0, 0, 0, 0, 0, 0};
    if ((quad >> 1) == (tp & 1)) {
      const float* xp = X + (size_t)sr * 16 + (quad & 1) * 8;
      float4 p = *(const float4*)xp;
      float4 q = *(const float4*)(xp + 4);
      av[0] = f2bf(p.x * nrm); av[1] = f2bf(p.y * nrm);
      av[2] = f2bf(p.z * nrm); av[3] = f2bf(p.w * nrm);
      av[4] = f2bf(q.x * nrm); av[5] = f2bf(q.y * nrm);
      av[6] = f2bf(q.z * nrm); av[7] = f2bf(q.w * nrm);
    }
    const int ma = tp >> 1;
    const bf16x8 z = {0, 0, 0, 0, 0, 0, 0, 0};
    bf16x8 a0 = (ma == 0) ? av : z;
    bf16x8 a1 = (ma == 1) ? av : z;
    bf16x8 a2 = (ma == 2) ? av : z;
    bf16x8 a3 = (ma == 3) ? av : z;

    f32x4 acc = {0.f, 0.f, 0.f, 0.f};
    acc = __builtin_amdgcn_mfma_f32_16x16x32_bf16(a0, b0, acc, 0, 0, 0);
    acc = __builtin_amdgcn_mfma_f32_16x16x32_bf16(a1, b1, acc, 0, 0, 0);
    acc = __builtin_amdgcn_mfma_f32_16x16x32_bf16(a2, b2, acc, 0, 0, 0);
    acc = __builtin_amdgcn_mfma_f32_16x16x32_bf16(a3, b3, acc, 0, 0, 0);

    // Scatter: lane holds D rows quad*4+r2, column col -> 16 consecutive
    // dwords per 16-lane group per r2 (coalesced atomic packets).
#pragma unroll
    for (int r2 = 0; r2 < 4; ++r2) {
      int row2 = quad * 4 + r2;
      int d2 = dst[e0 + row2];
      unsafeAtomicAdd(&agg[(size_t)d2 * 16 + col], acc[r2]);
    }
  }
}

// K4/K6: node pass. out = AGG + X@ROOT + BIAS, then relu (mode 0) or
// log_softmax over the 16 outputs (mode 1). One MFMA per 16-node tile,
// C preloaded with AGG+bias. K=32 with upper 16 k zero-padded.
__global__ void __launch_bounds__(256) node_kernel(
    const float* __restrict__ X, const float* __restrict__ ROOT,
    const float* __restrict__ BIAS, const float* __restrict__ AGG,
    float* __restrict__ OUT, const int mode) {
  const int lid  = threadIdx.x & 63;
  const int col  = lid & 15;
  const int quad = lid >> 4;
  const int wid  = (int)((blockIdx.x * 256u + threadIdx.x) >> 6);
  if (wid >= N_NODES / 16) return;
  const int n0 = wid * 16;

  bf16x8 br = {0, 0, 0, 0, 0, 0, 0, 0};
  bf16x8 av = {0, 0, 0, 0, 0, 0, 0, 0};
  if (quad < 2) {
#pragma unroll
    for (int j = 0; j < 8; ++j)
      br[j] = f2bf(ROOT[(quad * 8 + j) * 16 + col]);
    const float* xp = X + (size_t)(n0 + col) * 16 + quad * 8;
    float4 p = *(const float4*)xp;
    float4 q = *(const float4*)(xp + 4);
    av[0] = f2bf(p.x); av[1] = f2bf(p.y); av[2] = f2bf(p.z); av[3] = f2bf(p.w);
    av[4] = f2bf(q.x); av[5] = f2bf(q.y); av[6] = f2bf(q.z); av[7] = f2bf(q.w);
  }

  const float bc = BIAS[col];
  f32x4 c;
#pragma unroll
  for (int r2 = 0; r2 < 4; ++r2)
    c[r2] = AGG[(size_t)(n0 + quad * 4 + r2) * 16 + col] + bc;

  c = __builtin_amdgcn_mfma_f32_16x16x32_bf16(av, br, c, 0, 0, 0);

  if (mode == 0) {
#pragma unroll
    for (int r2 = 0; r2 < 4; ++r2)
      OUT[(size_t)(n0 + quad * 4 + r2) * 16 + col] = fmaxf(c[r2], 0.f);
  } else {
#pragma unroll
    for (int r2 = 0; r2 < 4; ++r2) {
      float zv = c[r2];
      float mx = zv;
      mx = fmaxf(mx, __shfl_xor(mx, 1));
      mx = fmaxf(mx, __shfl_xor(mx, 2));
      mx = fmaxf(mx, __shfl_xor(mx, 4));
      mx = fmaxf(mx, __shfl_xor(mx, 8));
      float sm = expf(zv - mx);
      sm += __shfl_xor(sm, 1);
      sm += __shfl_xor(sm, 2);
      sm += __shfl_xor(sm, 4);
      sm += __shfl_xor(sm, 8);
      OUT[(size_t)(n0 + quad * 4 + r2) * 16 + col] = zv - mx - logf(sm);
    }
  }
}

extern "C" void kernel_launch(void* const* d_in, const int* in_sizes, int n_in,
                              void* d_out, int out_size, void* d_ws, size_t ws_size,
                              hipStream_t stream) {
  const float* embed = (const float*)d_in[0];
  const float* W1    = (const float*)d_in[1];
  const float* root1 = (const float*)d_in[2];
  const float* b1    = (const float*)d_in[3];
  const float* W2    = (const float*)d_in[4];
  const float* root2 = (const float*)d_in[5];
  const float* b2    = (const float*)d_in[6];
  const int* eidx    = (const int*)d_in[7];
  const int* etyp    = (const int*)d_in[8];
  const int* src = eidx;
  const int* dst = eidx + N_EDGES;
  float* out = (float*)d_out;

  // Workspace layout (floats): cnt[800000] | invc[800000] | agg1[1.6M] | h[1.6M]
  float* ws = (float*)d_ws;
  unsigned* cnt = (unsigned*)ws;
  float* invc = ws + 800000;
  float* agg1 = ws + 1600000;
  float* h    = ws + 3200000;

  // Zero cnt + agg1 (invc fully overwritten, but contiguous memset is simpler),
  // and d_out (used as layer-2 scatter accumulator).
  hipMemsetAsync(d_ws, 0, (size_t)3200000 * 4, stream);
  hipMemsetAsync(d_out, 0, (size_t)1600000 * 4, stream);

  count_kernel<<<N_EDGES / 256, 256, 0, stream>>>(dst, etyp, cnt);
  inv_kernel<<<(N_NODES * NREL + 255) / 256, 256, 0, stream>>>(cnt, invc);

  // Layer 1
  edge_kernel<<<3125, 256, 0, stream>>>(embed, W1, invc, src, dst, etyp, agg1);
  node_kernel<<<1563, 256, 0, stream>>>(embed, root1, b1, agg1, h, 0);
  // Layer 2 (scatter directly into d_out, finalize in-place)
  edge_kernel<<<3125, 256, 0, stream>>>(h, W2, invc, src, dst, etyp, out);
  node_kernel<<<1563, 256, 0, stream>>>(h, root2, b2, out, out, 1);
}